// Round 1
// baseline (1136.943 us; speedup 1.0000x reference)
//
#include <hip/hip_runtime.h>
#include <math.h>

#define HID 64
#define NEG 0.2f
#define BSH 9         // bucket shift: 512 nodes per bucket
#define BNODES 512
#define CH 16384      // edges per chunk
#define NBMAX 256     // max buckets (n <= 131072)

typedef float f32x2 __attribute__((ext_vector_type(2)));

// ---------------- node transform: hf8 = fp8_e4m3(x@W), s = h.a_s, d = h.a_d
template <int CIN>
__global__ void transform_k(const float* __restrict__ xin,
                            const float* __restrict__ W,      // [CIN][64]
                            const float* __restrict__ avs,
                            const float* __restrict__ avd,
                            unsigned char* __restrict__ hf8,  // [n][64] fp8 e4m3
                            float* __restrict__ s_out, float* __restrict__ d_out,
                            int n) {
    __shared__ float Wl[CIN * HID];
    __shared__ float asl[HID], adl[HID];
    for (int i = threadIdx.x; i < CIN * HID; i += blockDim.x) Wl[i] = W[i];
    if (threadIdx.x < HID) { asl[threadIdx.x] = avs[threadIdx.x]; adl[threadIdx.x] = avd[threadIdx.x]; }
    __syncthreads();
    int lane = threadIdx.x & 63;
    int wid = (blockIdx.x * blockDim.x + threadIdx.x) >> 6;
    int nw = (gridDim.x * blockDim.x) >> 6;
    for (int i = wid; i < n; i += nw) {
        float hv = 0.f;
        if (CIN == 1) {
            hv = xin[i] * Wl[lane];
        } else {
            float xv = xin[(size_t)i * CIN + lane];
#pragma unroll
            for (int k = 0; k < CIN; ++k)
                hv += __shfl(xv, k) * Wl[k * HID + lane];
        }
        int pk = __builtin_amdgcn_cvt_pk_fp8_f32(hv, hv, 0, false);  // HW RNE cvt
        hf8[(size_t)i * HID + lane] = (unsigned char)(pk & 0xff);
        float sv = hv * asl[lane], dv = hv * adl[lane];
#pragma unroll
        for (int off = 32; off > 0; off >>= 1) {
            sv += __shfl_xor(sv, off);
            dv += __shfl_xor(dv, off);
        }
        if (lane == 0) { s_out[i] = sv; d_out[i] = dv; }
    }
}

// last layer transform: 64 -> 1; packs {s, hL} as float2 so agg1 does 1 gather/edge
__global__ void transform_last_k(const float* __restrict__ xin,
                                 const float* __restrict__ WL,
                                 const float* __restrict__ asL, const float* __restrict__ adL,
                                 float2* __restrict__ sh2,     // [n] {s_u, hL_u}
                                 float* __restrict__ d_out,
                                 int n) {
    __shared__ float Wl[HID];
    if (threadIdx.x < HID) Wl[threadIdx.x] = WL[threadIdx.x];
    __syncthreads();
    float aS = asL[0], aD = adL[0];
    int lane = threadIdx.x & 63;
    int wid = (blockIdx.x * blockDim.x + threadIdx.x) >> 6;
    int nw = (gridDim.x * blockDim.x) >> 6;
    for (int i = wid; i < n; i += nw) {
        float hv = xin[(size_t)i * HID + lane] * Wl[lane];
#pragma unroll
        for (int off = 32; off > 0; off >>= 1) hv += __shfl_xor(hv, off);
        if (lane == 0) {
            sh2[i] = make_float2(hv * aS, hv);
            d_out[i] = hv * aD;
        }
    }
}

// ---------------- CSR build: deterministic two-pass, ZERO global atomics ----------------
__global__ __launch_bounds__(256) void chunk_hist_k(const int* __restrict__ ei, int E, int nb,
                                                    int* __restrict__ counts) {
    __shared__ int lh[NBMAX];
    int t = threadIdx.x;
    int base = blockIdx.x * CH;
    int end = base + CH; if (end > E) end = E;
    for (int b = t; b < NBMAX; b += 256) lh[b] = 0;
    __syncthreads();
    for (int e = base + t; e < end; e += 256)
        atomicAdd(&lh[ei[E + e] >> BSH], 1);
    __syncthreads();
    for (int b = t; b < nb; b += 256)
        counts[(size_t)blockIdx.x * nb + b] = lh[b];
}

__global__ void col_scan_k(int* __restrict__ counts, int nchunks, int nb,
                           int* __restrict__ total) {
    int b = (blockIdx.x * blockDim.x + threadIdx.x) >> 6;
    int lane = threadIdx.x & 63;
    if (b >= nb) return;
    int run = 0;
    for (int c0 = 0; c0 < nchunks; c0 += 64) {
        int c = c0 + lane;
        int v = (c < nchunks) ? counts[(size_t)c * nb + b] : 0;
        int inc = v;
#pragma unroll
        for (int o = 1; o < 64; o <<= 1) {
            int w = __shfl_up(inc, o);
            if (lane >= o) inc += w;
        }
        int excl = inc - v + run;
        if (c < nchunks) counts[(size_t)c * nb + b] = excl;
        run += __shfl(inc, 63);
    }
    if (lane == 0) total[b] = run;
}

__global__ void bucket_scan_k(const int* __restrict__ total, int* __restrict__ pbase, int nb) {
    __shared__ int s[1024];
    int t = threadIdx.x;
    int v = (t < nb) ? total[t] : 0;
    s[t] = v;
    __syncthreads();
    for (int o = 1; o < 1024; o <<= 1) {
        int x = (t >= o) ? s[t - o] : 0;
        __syncthreads();
        s[t] += x;
        __syncthreads();
    }
    if (t < nb) {
        pbase[t] = s[t] - v;
        if (t == nb - 1) pbase[nb] = s[t];
    }
}

__global__ __launch_bounds__(256) void chunk_scatter_k(const int* __restrict__ ei, int E, int nb,
                                                       const int* __restrict__ counts,
                                                       const int* __restrict__ pbase,
                                                       unsigned* __restrict__ pairs) {
    __shared__ int lcur[NBMAX];
    int t = threadIdx.x;
    int c = blockIdx.x;
    int base = c * CH;
    int end = base + CH; if (end > E) end = E;
    for (int b = t; b < nb; b += 256)
        lcur[b] = pbase[b] + counts[(size_t)c * nb + b];
    __syncthreads();
    for (int e = base + t; e < end; e += 256) {
        int u = ei[e], v = ei[E + e];
        int b = v >> BSH;
        int pos = atomicAdd(&lcur[b], 1);
        pairs[pos] = ((unsigned)u << BSH) | (unsigned)(v & (BNODES - 1));
    }
}

__global__ __launch_bounds__(512) void csr_build_k(const unsigned* __restrict__ pairs,
                                                   const int* __restrict__ pbase,
                                                   int nb, int n,
                                                   int* __restrict__ off, int* __restrict__ csr) {
    __shared__ int cnt[BNODES];
    __shared__ int sc[BNODES];
    __shared__ int cur[BNODES];
    int b = blockIdx.x;
    int pb = pbase[b], pe = pbase[b + 1];
    int node0 = b << BSH;
    int nnode = n - node0; if (nnode > BNODES) nnode = BNODES;
    int cbase = pb + node0;
    int t = threadIdx.x;
    cnt[t] = 0;
    __syncthreads();
    for (int i = pb + t; i < pe; i += blockDim.x)
        atomicAdd(&cnt[pairs[i] & (BNODES - 1)], 1);
    __syncthreads();
    int deg = (t < nnode) ? cnt[t] + 1 : 0;   // +1 self loop
    sc[t] = deg;
    __syncthreads();
#pragma unroll
    for (int o = 1; o < BNODES; o <<= 1) {
        int x = (t >= o) ? sc[t - o] : 0;
        __syncthreads();
        sc[t] += x;
        __syncthreads();
    }
    if (t < nnode) {
        int excl = sc[t] - deg;
        off[node0 + t] = cbase + excl;
        cur[t] = excl;
        csr[cbase + excl + cnt[t]] = node0 + t;    // self-loop slot
    }
    if (b == nb - 1 && t == 0) off[n] = cbase + sc[BNODES - 1];
    __syncthreads();
    for (int i = pb + t; i < pe; i += blockDim.x) {
        unsigned p = pairs[i];
        int j = p & (BNODES - 1);
        int pos = atomicAdd(&cur[j], 1);
        csr[cbase + pos] = (int)(p >> BSH);
    }
}

// ---------------- fused softmax+aggregate, latency-optimized.
// Softmax is shift-invariant; logits bounded so exp() cannot overflow.
// Layout: 4 lanes/edge (sub = lane&3 owns 16 channels), q = lane>>2 gives
// 16 edge slots. Each lane REDUNDANTLY computes e for its own 4 edges
// (exp is cheap; VALUBusy had headroom) — this removes the LDS exchange and
// the phase-1/phase-2 serialization entirely. Per 64-edge block the chain is:
// 4 independent csr loads -> 8 independent dependent loads (4x s, 4x uint4
// fp8 row = one 64B line each) all in flight -> pure VALU. 4-deep unroll is
// sized so a mean-degree node (~65) does exactly one main iteration.
__global__ __launch_bounds__(256) void gat_agg_k(
    const int* __restrict__ off, const int* __restrict__ csr,
    const float* __restrict__ s, const float* __restrict__ d,
    const unsigned char* __restrict__ hf8, const float* __restrict__ b,
    float* __restrict__ out, int n) {
    int lane = threadIdx.x & 63;
    int sub = lane & 3;         // channel group: channels sub*16 .. sub*16+15
    int q = lane >> 2;          // edge slot 0..15
    int ch = sub * 16;
    int wid = (blockIdx.x * blockDim.x + threadIdx.x) >> 6;
    int nw = (gridDim.x * blockDim.x) >> 6;
    for (int v = wid; v < n; v += nw) {
        int beg = off[v];
        int deg = off[v + 1] - beg;
        float dv = d[v];
        float l = 0.f;
        f32x2 a0 = {0.f, 0.f}, a1 = {0.f, 0.f}, a2 = {0.f, 0.f}, a3 = {0.f, 0.f};
        f32x2 a4 = {0.f, 0.f}, a5 = {0.f, 0.f}, a6 = {0.f, 0.f}, a7 = {0.f, 0.f};
        int k = q;
        for (; k + 48 < deg; k += 64) {
            const int* cp = csr + beg + k;
            int u0 = cp[0];
            int u1 = cp[16];
            int u2 = cp[32];
            int u3 = cp[48];
            const uint4 h0 = *(const uint4*)&hf8[(size_t)u0 * HID + ch];
            const uint4 h1 = *(const uint4*)&hf8[(size_t)u1 * HID + ch];
            const uint4 h2 = *(const uint4*)&hf8[(size_t)u2 * HID + ch];
            const uint4 h3 = *(const uint4*)&hf8[(size_t)u3 * HID + ch];
            float t0 = s[u0] + dv, t1 = s[u1] + dv, t2 = s[u2] + dv, t3 = s[u3] + dv;
            t0 = t0 > 0.f ? t0 : NEG * t0;
            t1 = t1 > 0.f ? t1 : NEG * t1;
            t2 = t2 > 0.f ? t2 : NEG * t2;
            t3 = t3 > 0.f ? t3 : NEG * t3;
            float e0 = __expf(t0), e1 = __expf(t1), e2 = __expf(t2), e3 = __expf(t3);
            l += (e0 + e1) + (e2 + e3);
            f32x2 E;
            E.x = e0; E.y = e0;
            a0 += E * (f32x2)__builtin_amdgcn_cvt_pk_f32_fp8(h0.x, false);
            a1 += E * (f32x2)__builtin_amdgcn_cvt_pk_f32_fp8(h0.x, true);
            a2 += E * (f32x2)__builtin_amdgcn_cvt_pk_f32_fp8(h0.y, false);
            a3 += E * (f32x2)__builtin_amdgcn_cvt_pk_f32_fp8(h0.y, true);
            a4 += E * (f32x2)__builtin_amdgcn_cvt_pk_f32_fp8(h0.z, false);
            a5 += E * (f32x2)__builtin_amdgcn_cvt_pk_f32_fp8(h0.z, true);
            a6 += E * (f32x2)__builtin_amdgcn_cvt_pk_f32_fp8(h0.w, false);
            a7 += E * (f32x2)__builtin_amdgcn_cvt_pk_f32_fp8(h0.w, true);
            E.x = e1; E.y = e1;
            a0 += E * (f32x2)__builtin_amdgcn_cvt_pk_f32_fp8(h1.x, false);
            a1 += E * (f32x2)__builtin_amdgcn_cvt_pk_f32_fp8(h1.x, true);
            a2 += E * (f32x2)__builtin_amdgcn_cvt_pk_f32_fp8(h1.y, false);
            a3 += E * (f32x2)__builtin_amdgcn_cvt_pk_f32_fp8(h1.y, true);
            a4 += E * (f32x2)__builtin_amdgcn_cvt_pk_f32_fp8(h1.z, false);
            a5 += E * (f32x2)__builtin_amdgcn_cvt_pk_f32_fp8(h1.z, true);
            a6 += E * (f32x2)__builtin_amdgcn_cvt_pk_f32_fp8(h1.w, false);
            a7 += E * (f32x2)__builtin_amdgcn_cvt_pk_f32_fp8(h1.w, true);
            E.x = e2; E.y = e2;
            a0 += E * (f32x2)__builtin_amdgcn_cvt_pk_f32_fp8(h2.x, false);
            a1 += E * (f32x2)__builtin_amdgcn_cvt_pk_f32_fp8(h2.x, true);
            a2 += E * (f32x2)__builtin_amdgcn_cvt_pk_f32_fp8(h2.y, false);
            a3 += E * (f32x2)__builtin_amdgcn_cvt_pk_f32_fp8(h2.y, true);
            a4 += E * (f32x2)__builtin_amdgcn_cvt_pk_f32_fp8(h2.z, false);
            a5 += E * (f32x2)__builtin_amdgcn_cvt_pk_f32_fp8(h2.z, true);
            a6 += E * (f32x2)__builtin_amdgcn_cvt_pk_f32_fp8(h2.w, false);
            a7 += E * (f32x2)__builtin_amdgcn_cvt_pk_f32_fp8(h2.w, true);
            E.x = e3; E.y = e3;
            a0 += E * (f32x2)__builtin_amdgcn_cvt_pk_f32_fp8(h3.x, false);
            a1 += E * (f32x2)__builtin_amdgcn_cvt_pk_f32_fp8(h3.x, true);
            a2 += E * (f32x2)__builtin_amdgcn_cvt_pk_f32_fp8(h3.y, false);
            a3 += E * (f32x2)__builtin_amdgcn_cvt_pk_f32_fp8(h3.y, true);
            a4 += E * (f32x2)__builtin_amdgcn_cvt_pk_f32_fp8(h3.z, false);
            a5 += E * (f32x2)__builtin_amdgcn_cvt_pk_f32_fp8(h3.z, true);
            a6 += E * (f32x2)__builtin_amdgcn_cvt_pk_f32_fp8(h3.w, false);
            a7 += E * (f32x2)__builtin_amdgcn_cvt_pk_f32_fp8(h3.w, true);
        }
        for (; k < deg; k += 16) {
            int u = csr[beg + k];
            const uint4 hv = *(const uint4*)&hf8[(size_t)u * HID + ch];
            float t = s[u] + dv;
            t = t > 0.f ? t : NEG * t;
            float e = __expf(t);
            l += e;
            f32x2 E; E.x = e; E.y = e;
            a0 += E * (f32x2)__builtin_amdgcn_cvt_pk_f32_fp8(hv.x, false);
            a1 += E * (f32x2)__builtin_amdgcn_cvt_pk_f32_fp8(hv.x, true);
            a2 += E * (f32x2)__builtin_amdgcn_cvt_pk_f32_fp8(hv.y, false);
            a3 += E * (f32x2)__builtin_amdgcn_cvt_pk_f32_fp8(hv.y, true);
            a4 += E * (f32x2)__builtin_amdgcn_cvt_pk_f32_fp8(hv.z, false);
            a5 += E * (f32x2)__builtin_amdgcn_cvt_pk_f32_fp8(hv.z, true);
            a6 += E * (f32x2)__builtin_amdgcn_cvt_pk_f32_fp8(hv.w, false);
            a7 += E * (f32x2)__builtin_amdgcn_cvt_pk_f32_fp8(hv.w, true);
        }
        // reduce across the 16 edge slots (q bits = lane bits 2..5).
        // l per lane covers only its own q edges, so this sum counts each
        // edge exactly once per sub-group — no overcount correction needed.
#pragma unroll
        for (int o = 4; o < 64; o <<= 1) {
            a0.x += __shfl_xor(a0.x, o); a0.y += __shfl_xor(a0.y, o);
            a1.x += __shfl_xor(a1.x, o); a1.y += __shfl_xor(a1.y, o);
            a2.x += __shfl_xor(a2.x, o); a2.y += __shfl_xor(a2.y, o);
            a3.x += __shfl_xor(a3.x, o); a3.y += __shfl_xor(a3.y, o);
            a4.x += __shfl_xor(a4.x, o); a4.y += __shfl_xor(a4.y, o);
            a5.x += __shfl_xor(a5.x, o); a5.y += __shfl_xor(a5.y, o);
            a6.x += __shfl_xor(a6.x, o); a6.y += __shfl_xor(a6.y, o);
            a7.x += __shfl_xor(a7.x, o); a7.y += __shfl_xor(a7.y, o);
            l += __shfl_xor(l, o);
        }
        if (q == 0) {
            float inv = 1.f / l;
            const float4 bb0 = *(const float4*)&b[ch];
            const float4 bb1 = *(const float4*)&b[ch + 4];
            const float4 bb2 = *(const float4*)&b[ch + 8];
            const float4 bb3 = *(const float4*)&b[ch + 12];
            float4 r0, r1, r2, r3;
            r0.x = a0.x * inv + bb0.x; r0.y = a0.y * inv + bb0.y;
            r0.z = a1.x * inv + bb0.z; r0.w = a1.y * inv + bb0.w;
            r1.x = a2.x * inv + bb1.x; r1.y = a2.y * inv + bb1.y;
            r1.z = a3.x * inv + bb1.z; r1.w = a3.y * inv + bb1.w;
            r2.x = a4.x * inv + bb2.x; r2.y = a4.y * inv + bb2.y;
            r2.z = a5.x * inv + bb2.z; r2.w = a5.y * inv + bb2.w;
            r3.x = a6.x * inv + bb3.x; r3.y = a6.y * inv + bb3.y;
            r3.z = a7.x * inv + bb3.z; r3.w = a7.y * inv + bb3.w;
            r0.x = r0.x > 0.f ? r0.x : 0.f; r0.y = r0.y > 0.f ? r0.y : 0.f;
            r0.z = r0.z > 0.f ? r0.z : 0.f; r0.w = r0.w > 0.f ? r0.w : 0.f;
            r1.x = r1.x > 0.f ? r1.x : 0.f; r1.y = r1.y > 0.f ? r1.y : 0.f;
            r1.z = r1.z > 0.f ? r1.z : 0.f; r1.w = r1.w > 0.f ? r1.w : 0.f;
            r2.x = r2.x > 0.f ? r2.x : 0.f; r2.y = r2.y > 0.f ? r2.y : 0.f;
            r2.z = r2.z > 0.f ? r2.z : 0.f; r2.w = r2.w > 0.f ? r2.w : 0.f;
            r3.x = r3.x > 0.f ? r3.x : 0.f; r3.y = r3.y > 0.f ? r3.y : 0.f;
            r3.z = r3.z > 0.f ? r3.z : 0.f; r3.w = r3.w > 0.f ? r3.w : 0.f;
            *(float4*)&out[(size_t)v * HID + ch] = r0;
            *(float4*)&out[(size_t)v * HID + ch + 4] = r1;
            *(float4*)&out[(size_t)v * HID + ch + 8] = r2;
            *(float4*)&out[(size_t)v * HID + ch + 12] = r3;
        }
    }
}

// last layer aggregate (1 channel): single gather/edge ({s,hL} packed), 4-way unroll
__global__ void gat_agg1_k(const int* __restrict__ off, const int* __restrict__ csr,
                           const float2* __restrict__ sh2, const float* __restrict__ d,
                           const float* __restrict__ bL,
                           float* __restrict__ out, int n) {
    int lane = threadIdx.x & 63;
    int wid = (blockIdx.x * blockDim.x + threadIdx.x) >> 6;
    int nw = (gridDim.x * blockDim.x) >> 6;
    float bias = bL[0];
    for (int v = wid; v < n; v += nw) {
        int beg = off[v], end = off[v + 1];
        float dv = d[v];
        float l = 0.f, acc = 0.f;
        int i = beg + lane;
        for (; i + 192 < end; i += 256) {   // 4 edges in flight per lane
            int u0 = csr[i], u1 = csr[i + 64], u2 = csr[i + 128], u3 = csr[i + 192];
            float2 p0 = sh2[u0], p1 = sh2[u1], p2 = sh2[u2], p3 = sh2[u3];
            float t0 = p0.x + dv, t1 = p1.x + dv, t2 = p2.x + dv, t3 = p3.x + dv;
            t0 = t0 > 0.f ? t0 : NEG * t0; t1 = t1 > 0.f ? t1 : NEG * t1;
            t2 = t2 > 0.f ? t2 : NEG * t2; t3 = t3 > 0.f ? t3 : NEG * t3;
            float e0 = __expf(t0), e1 = __expf(t1), e2 = __expf(t2), e3 = __expf(t3);
            l += e0 + e1 + e2 + e3;
            acc += e0 * p0.y + e1 * p1.y + e2 * p2.y + e3 * p3.y;
        }
        for (; i < end; i += 64) {
            int u = csr[i];
            float2 p = sh2[u];
            float t = p.x + dv;
            t = t > 0.f ? t : NEG * t;
            float e = __expf(t);
            l += e;
            acc += e * p.y;
        }
#pragma unroll
        for (int o = 32; o > 0; o >>= 1) {
            l += __shfl_xor(l, o);
            acc += __shfl_xor(acc, o);
        }
        if (lane == 0) {
            float r = acc / l + bias;
            out[v] = 1.f / (1.f + __expf(-r));  // sigmoid
        }
    }
}

extern "C" void kernel_launch(void* const* d_in, const int* in_sizes, int n_in,
                              void* d_out, int out_size, void* d_ws, size_t ws_size,
                              hipStream_t stream) {
    const float* x   = (const float*)d_in[0];
    const int*   ei  = (const int*)d_in[1];
    // d_in[2] = edge_weight: ignored (edge_dim=None)
    const float* W0  = (const float*)d_in[3];
    const float* as0 = (const float*)d_in[4];
    const float* ad0 = (const float*)d_in[5];
    const float* b0  = (const float*)d_in[6];
    const float* Wm  = (const float*)d_in[7];
    const float* asm_ = (const float*)d_in[8];
    const float* adm = (const float*)d_in[9];
    const float* bm  = (const float*)d_in[10];
    const float* WL  = (const float*)d_in[11];
    const float* asL = (const float*)d_in[12];
    const float* adL = (const float*)d_in[13];
    const float* bL  = (const float*)d_in[14];

    const int n = in_sizes[0];      // 100000
    const int E = in_sizes[1] / 2;  // 6400000
    const int nb = (n + BNODES - 1) >> BSH;  // 196 buckets
    const int gChunk = (E + CH - 1) / CH;    // 391 chunks

    // workspace: h[n*64]f (hf8/sh2 alias; counts[] aliases during CSR build) |
    //            A[n*64]f (pairs[] aliases during CSR build) |
    //            s[n] | d[n] | off[n+1] | csr[E+n] | total[nb] | pbase[nb+1]
    float* ws   = (float*)d_ws;
    float* h    = ws;
    unsigned char* hf8 = (unsigned char*)ws;
    float2* sh2 = (float2*)ws;
    float* A    = ws + (size_t)n * HID;
    float* sbuf = ws + 2 * (size_t)n * HID;
    float* dbuf = sbuf + n;
    int* off    = (int*)(dbuf + n);
    int* csr    = off + n + 1;
    int* total  = csr + E + n;
    int* pbase  = total + nb;
    int* counts = (int*)h;            // gChunk*nb ints << region; pre-transform only
    unsigned* pairs = (unsigned*)A;   // E ints; pre-agg only

    const int BLK = 256;
    const int gTrans = 2048;
    const int gAgg   = (n + 3) / 4;   // 1 node per wave

    // ---- CSR build (deterministic bases; zero global atomics)
    chunk_hist_k<<<gChunk, BLK, 0, stream>>>(ei, E, nb, counts);
    col_scan_k<<<(nb + 3) / 4, BLK, 0, stream>>>(counts, gChunk, nb, total);
    bucket_scan_k<<<1, 1024, 0, stream>>>(total, pbase, nb);
    chunk_scatter_k<<<gChunk, BLK, 0, stream>>>(ei, E, nb, counts, pbase, pairs);
    csr_build_k<<<nb, 512, 0, stream>>>(pairs, pbase, nb, n, off, csr);

    // ---- layer 0: 1 -> 64, ReLU
    transform_k<1><<<gTrans, BLK, 0, stream>>>(x, W0, as0, ad0, hf8, sbuf, dbuf, n);
    gat_agg_k<<<gAgg, BLK, 0, stream>>>(off, csr, sbuf, dbuf, hf8, b0, A, n);

    // ---- middle layers: 64 -> 64, ReLU
    for (int l = 0; l < 3; ++l) {
        transform_k<64><<<gTrans, BLK, 0, stream>>>(A, Wm + (size_t)l * HID * HID,
                                                    asm_ + l * HID, adm + l * HID,
                                                    hf8, sbuf, dbuf, n);
        gat_agg_k<<<gAgg, BLK, 0, stream>>>(off, csr, sbuf, dbuf, hf8, bm + l * HID, A, n);
    }

    // ---- last layer: 64 -> 1, sigmoid ({s,hL} packed into sh2, aliasing h region)
    transform_last_k<<<gTrans, BLK, 0, stream>>>(A, WL, asL, adL, sh2, dbuf, n);
    gat_agg1_k<<<gAgg, BLK, 0, stream>>>(off, csr, sh2, dbuf, bL, (float*)d_out, n);
}

// Round 2
// 940.976 us; speedup vs baseline: 1.2083x; 1.2083x over previous
//
#include <hip/hip_runtime.h>
#include <math.h>

#define HID 64
#define NEG 0.2f
#define BSH 9         // bucket shift: 512 nodes per bucket
#define BNODES 512
#define CH 16384      // edges per chunk
#define NBMAX 256     // max buckets (n <= 131072)

typedef float f32x2 __attribute__((ext_vector_type(2)));

// ---------------- node transform: hf8 = fp8_e4m3(x@W), s = h.a_s, d = h.a_d
template <int CIN>
__global__ void transform_k(const float* __restrict__ xin,
                            const float* __restrict__ W,      // [CIN][64]
                            const float* __restrict__ avs,
                            const float* __restrict__ avd,
                            unsigned char* __restrict__ hf8,  // [n][64] fp8 e4m3
                            float* __restrict__ s_out, float* __restrict__ d_out,
                            int n) {
    __shared__ float Wl[CIN * HID];
    __shared__ float asl[HID], adl[HID];
    for (int i = threadIdx.x; i < CIN * HID; i += blockDim.x) Wl[i] = W[i];
    if (threadIdx.x < HID) { asl[threadIdx.x] = avs[threadIdx.x]; adl[threadIdx.x] = avd[threadIdx.x]; }
    __syncthreads();
    int lane = threadIdx.x & 63;
    int wid = (blockIdx.x * blockDim.x + threadIdx.x) >> 6;
    int nw = (gridDim.x * blockDim.x) >> 6;
    for (int i = wid; i < n; i += nw) {
        float hv = 0.f;
        if (CIN == 1) {
            hv = xin[i] * Wl[lane];
        } else {
            float xv = xin[(size_t)i * CIN + lane];
#pragma unroll
            for (int k = 0; k < CIN; ++k)
                hv += __shfl(xv, k) * Wl[k * HID + lane];
        }
        int pk = __builtin_amdgcn_cvt_pk_fp8_f32(hv, hv, 0, false);  // HW RNE cvt
        hf8[(size_t)i * HID + lane] = (unsigned char)(pk & 0xff);
        float sv = hv * asl[lane], dv = hv * adl[lane];
#pragma unroll
        for (int off = 32; off > 0; off >>= 1) {
            sv += __shfl_xor(sv, off);
            dv += __shfl_xor(dv, off);
        }
        if (lane == 0) { s_out[i] = sv; d_out[i] = dv; }
    }
}

// last layer transform: 64 -> 1; packs {s, hL} as float2 so agg1 does 1 gather/edge
__global__ void transform_last_k(const float* __restrict__ xin,
                                 const float* __restrict__ WL,
                                 const float* __restrict__ asL, const float* __restrict__ adL,
                                 float2* __restrict__ sh2,     // [n] {s_u, hL_u}
                                 float* __restrict__ d_out,
                                 int n) {
    __shared__ float Wl[HID];
    if (threadIdx.x < HID) Wl[threadIdx.x] = WL[threadIdx.x];
    __syncthreads();
    float aS = asL[0], aD = adL[0];
    int lane = threadIdx.x & 63;
    int wid = (blockIdx.x * blockDim.x + threadIdx.x) >> 6;
    int nw = (gridDim.x * blockDim.x) >> 6;
    for (int i = wid; i < n; i += nw) {
        float hv = xin[(size_t)i * HID + lane] * Wl[lane];
#pragma unroll
        for (int off = 32; off > 0; off >>= 1) hv += __shfl_xor(hv, off);
        if (lane == 0) {
            sh2[i] = make_float2(hv * aS, hv);
            d_out[i] = hv * aD;
        }
    }
}

// ---------------- CSR build: deterministic two-pass, ZERO global atomics ----------------
__global__ __launch_bounds__(256) void chunk_hist_k(const int* __restrict__ ei, int E, int nb,
                                                    int* __restrict__ counts) {
    __shared__ int lh[NBMAX];
    int t = threadIdx.x;
    int base = blockIdx.x * CH;
    int end = base + CH; if (end > E) end = E;
    for (int b = t; b < NBMAX; b += 256) lh[b] = 0;
    __syncthreads();
    for (int e = base + t; e < end; e += 256)
        atomicAdd(&lh[ei[E + e] >> BSH], 1);
    __syncthreads();
    for (int b = t; b < nb; b += 256)
        counts[(size_t)blockIdx.x * nb + b] = lh[b];
}

__global__ void col_scan_k(int* __restrict__ counts, int nchunks, int nb,
                           int* __restrict__ total) {
    int b = (blockIdx.x * blockDim.x + threadIdx.x) >> 6;
    int lane = threadIdx.x & 63;
    if (b >= nb) return;
    int run = 0;
    for (int c0 = 0; c0 < nchunks; c0 += 64) {
        int c = c0 + lane;
        int v = (c < nchunks) ? counts[(size_t)c * nb + b] : 0;
        int inc = v;
#pragma unroll
        for (int o = 1; o < 64; o <<= 1) {
            int w = __shfl_up(inc, o);
            if (lane >= o) inc += w;
        }
        int excl = inc - v + run;
        if (c < nchunks) counts[(size_t)c * nb + b] = excl;
        run += __shfl(inc, 63);
    }
    if (lane == 0) total[b] = run;
}

__global__ void bucket_scan_k(const int* __restrict__ total, int* __restrict__ pbase, int nb) {
    __shared__ int s[1024];
    int t = threadIdx.x;
    int v = (t < nb) ? total[t] : 0;
    s[t] = v;
    __syncthreads();
    for (int o = 1; o < 1024; o <<= 1) {
        int x = (t >= o) ? s[t - o] : 0;
        __syncthreads();
        s[t] += x;
        __syncthreads();
    }
    if (t < nb) {
        pbase[t] = s[t] - v;
        if (t == nb - 1) pbase[nb] = s[t];
    }
}

__global__ __launch_bounds__(256) void chunk_scatter_k(const int* __restrict__ ei, int E, int nb,
                                                       const int* __restrict__ counts,
                                                       const int* __restrict__ pbase,
                                                       unsigned* __restrict__ pairs) {
    __shared__ int lcur[NBMAX];
    int t = threadIdx.x;
    int c = blockIdx.x;
    int base = c * CH;
    int end = base + CH; if (end > E) end = E;
    for (int b = t; b < nb; b += 256)
        lcur[b] = pbase[b] + counts[(size_t)c * nb + b];
    __syncthreads();
    for (int e = base + t; e < end; e += 256) {
        int u = ei[e], v = ei[E + e];
        int b = v >> BSH;
        int pos = atomicAdd(&lcur[b], 1);
        pairs[pos] = ((unsigned)u << BSH) | (unsigned)(v & (BNODES - 1));
    }
}

__global__ __launch_bounds__(512) void csr_build_k(const unsigned* __restrict__ pairs,
                                                   const int* __restrict__ pbase,
                                                   int nb, int n,
                                                   int* __restrict__ off, int* __restrict__ csr) {
    __shared__ int cnt[BNODES];
    __shared__ int sc[BNODES];
    __shared__ int cur[BNODES];
    int b = blockIdx.x;
    int pb = pbase[b], pe = pbase[b + 1];
    int node0 = b << BSH;
    int nnode = n - node0; if (nnode > BNODES) nnode = BNODES;
    int cbase = pb + node0;
    int t = threadIdx.x;
    cnt[t] = 0;
    __syncthreads();
    for (int i = pb + t; i < pe; i += blockDim.x)
        atomicAdd(&cnt[pairs[i] & (BNODES - 1)], 1);
    __syncthreads();
    int deg = (t < nnode) ? cnt[t] + 1 : 0;   // +1 self loop
    sc[t] = deg;
    __syncthreads();
#pragma unroll
    for (int o = 1; o < BNODES; o <<= 1) {
        int x = (t >= o) ? sc[t - o] : 0;
        __syncthreads();
        sc[t] += x;
        __syncthreads();
    }
    if (t < nnode) {
        int excl = sc[t] - deg;
        off[node0 + t] = cbase + excl;
        cur[t] = excl;
        csr[cbase + excl + cnt[t]] = node0 + t;    // self-loop slot
    }
    if (b == nb - 1 && t == 0) off[n] = cbase + sc[BNODES - 1];
    __syncthreads();
    for (int i = pb + t; i < pe; i += blockDim.x) {
        unsigned p = pairs[i];
        int j = p & (BNODES - 1);
        int pos = atomicAdd(&cur[j], 1);
        csr[cbase + pos] = (int)(p >> BSH);
    }
}

// ---------------- fused softmax+aggregate (R0 structure, 128-edge blocks).
// Softmax is shift-invariant; logits bounded so exp() cannot overflow.
// Lane owns up to TWO edges for exp (128-edge block => one phase boundary per
// node at mean deg ~65, vs two with 64-edge blocks); exchanges {e,u} via
// wave-local LDS; 8 lanes/edge for channel FMAs (uint2 = 8 fp8 per lane,
// one 64B line per row). ALL 128 LDS slots are written (e=0,u=0 for invalid)
// so phase 2 is branch-free uniform groups of 32 slots with 4 independent
// ds_read->gather pairs in flight; dead slots gather the L1-hot row 0 and
// contribute exactly 0. launch_bounds(256,8) pins the 8-waves/SIMD VGPR
// budget (R1 lesson: occupancy is worth more than per-wave ILP here).
__global__ __launch_bounds__(256, 8) void gat_agg_k(
    const int* __restrict__ off, const int* __restrict__ csr,
    const float* __restrict__ s, const float* __restrict__ d,
    const unsigned char* __restrict__ hf8, const float* __restrict__ b,
    float* __restrict__ out, int n) {
    __shared__ uint2 eu_lds[4][128];
    int lane = threadIdx.x & 63;
    int wsub = threadIdx.x >> 6;
    int sub = lane & 7;         // channel group: channels sub*8 .. sub*8+7
    int q = lane >> 3;          // edge slot 0..7 (mod 8)
    int ch = sub * 8;
    int wid = (blockIdx.x * blockDim.x + threadIdx.x) >> 6;
    int nw = (gridDim.x * blockDim.x) >> 6;
    uint2* eup = eu_lds[wsub];
    float4 bb0 = *(const float4*)&b[ch];
    float4 bb1 = *(const float4*)&b[ch + 4];
    for (int v = wid; v < n; v += nw) {
        int beg = off[v];
        int deg = off[v + 1] - beg;
        float dv = d[v];
        float l = 0.f;
        f32x2 a01 = {0.f, 0.f}, a23 = {0.f, 0.f}, a45 = {0.f, 0.f}, a67 = {0.f, 0.f};
        for (int base = 0; base < deg; base += 128) {
            int rem = deg - base;
            int kmax = rem < 128 ? rem : 128;
            // phase 1: two independent edge chains per lane; exp once per edge
            unsigned ua = 0u, ub = 0u;
            float ea = 0.f, eb = 0.f;
            bool va = lane < kmax, vb = lane + 64 < kmax;
            if (va) ua = (unsigned)csr[beg + base + lane];
            if (vb) ub = (unsigned)csr[beg + base + 64 + lane];
            float sa = va ? s[ua] : 0.f;
            float sb = vb ? s[ub] : 0.f;
            if (va) {
                float t = sa + dv;
                t = t > 0.f ? t : NEG * t;
                ea = __expf(t);
            }
            if (vb) {
                float t = sb + dv;
                t = t > 0.f ? t : NEG * t;
                eb = __expf(t);
            }
            l += ea + eb;
            eup[lane] = make_uint2(__float_as_uint(ea), ua);
            eup[64 + lane] = make_uint2(__float_as_uint(eb), ub);
            // phase 2: uniform groups of 32 slots, 4 gathers in flight
            for (int k0 = 0; k0 < kmax; k0 += 32) {
                uint2 e0 = eup[k0 + q];
                uint2 e1 = eup[k0 + q + 8];
                uint2 e2 = eup[k0 + q + 16];
                uint2 e3 = eup[k0 + q + 24];
                uint2 h0 = *(const uint2*)&hf8[(size_t)e0.y * HID + ch];
                uint2 h1 = *(const uint2*)&hf8[(size_t)e1.y * HID + ch];
                uint2 h2 = *(const uint2*)&hf8[(size_t)e2.y * HID + ch];
                uint2 h3 = *(const uint2*)&hf8[(size_t)e3.y * HID + ch];
                f32x2 E;
                E.x = __uint_as_float(e0.x); E.y = E.x;
                a01 += E * (f32x2)__builtin_amdgcn_cvt_pk_f32_fp8(h0.x, false);
                a23 += E * (f32x2)__builtin_amdgcn_cvt_pk_f32_fp8(h0.x, true);
                a45 += E * (f32x2)__builtin_amdgcn_cvt_pk_f32_fp8(h0.y, false);
                a67 += E * (f32x2)__builtin_amdgcn_cvt_pk_f32_fp8(h0.y, true);
                E.x = __uint_as_float(e1.x); E.y = E.x;
                a01 += E * (f32x2)__builtin_amdgcn_cvt_pk_f32_fp8(h1.x, false);
                a23 += E * (f32x2)__builtin_amdgcn_cvt_pk_f32_fp8(h1.x, true);
                a45 += E * (f32x2)__builtin_amdgcn_cvt_pk_f32_fp8(h1.y, false);
                a67 += E * (f32x2)__builtin_amdgcn_cvt_pk_f32_fp8(h1.y, true);
                E.x = __uint_as_float(e2.x); E.y = E.x;
                a01 += E * (f32x2)__builtin_amdgcn_cvt_pk_f32_fp8(h2.x, false);
                a23 += E * (f32x2)__builtin_amdgcn_cvt_pk_f32_fp8(h2.x, true);
                a45 += E * (f32x2)__builtin_amdgcn_cvt_pk_f32_fp8(h2.y, false);
                a67 += E * (f32x2)__builtin_amdgcn_cvt_pk_f32_fp8(h2.y, true);
                E.x = __uint_as_float(e3.x); E.y = E.x;
                a01 += E * (f32x2)__builtin_amdgcn_cvt_pk_f32_fp8(h3.x, false);
                a23 += E * (f32x2)__builtin_amdgcn_cvt_pk_f32_fp8(h3.x, true);
                a45 += E * (f32x2)__builtin_amdgcn_cvt_pk_f32_fp8(h3.y, false);
                a67 += E * (f32x2)__builtin_amdgcn_cvt_pk_f32_fp8(h3.y, true);
            }
        }
        // reduce: acc over the 8 edge slots (q); l over all 64 lanes
#pragma unroll
        for (int o = 8; o < 64; o <<= 1) {
            a01.x += __shfl_xor(a01.x, o); a01.y += __shfl_xor(a01.y, o);
            a23.x += __shfl_xor(a23.x, o); a23.y += __shfl_xor(a23.y, o);
            a45.x += __shfl_xor(a45.x, o); a45.y += __shfl_xor(a45.y, o);
            a67.x += __shfl_xor(a67.x, o); a67.y += __shfl_xor(a67.y, o);
        }
#pragma unroll
        for (int o = 1; o < 64; o <<= 1) l += __shfl_xor(l, o);
        if (q == 0) {
            float inv = 1.f / l;
            float4 r0, r1;
            r0.x = a01.x * inv + bb0.x; r0.y = a01.y * inv + bb0.y;
            r0.z = a23.x * inv + bb0.z; r0.w = a23.y * inv + bb0.w;
            r1.x = a45.x * inv + bb1.x; r1.y = a45.y * inv + bb1.y;
            r1.z = a67.x * inv + bb1.z; r1.w = a67.y * inv + bb1.w;
            r0.x = r0.x > 0.f ? r0.x : 0.f; r0.y = r0.y > 0.f ? r0.y : 0.f;
            r0.z = r0.z > 0.f ? r0.z : 0.f; r0.w = r0.w > 0.f ? r0.w : 0.f;
            r1.x = r1.x > 0.f ? r1.x : 0.f; r1.y = r1.y > 0.f ? r1.y : 0.f;
            r1.z = r1.z > 0.f ? r1.z : 0.f; r1.w = r1.w > 0.f ? r1.w : 0.f;
            *(float4*)&out[(size_t)v * HID + ch] = r0;
            *(float4*)&out[(size_t)v * HID + ch + 4] = r1;
        }
    }
}

// last layer aggregate (1 channel): single gather/edge ({s,hL} packed), 4-way unroll
__global__ void gat_agg1_k(const int* __restrict__ off, const int* __restrict__ csr,
                           const float2* __restrict__ sh2, const float* __restrict__ d,
                           const float* __restrict__ bL,
                           float* __restrict__ out, int n) {
    int lane = threadIdx.x & 63;
    int wid = (blockIdx.x * blockDim.x + threadIdx.x) >> 6;
    int nw = (gridDim.x * blockDim.x) >> 6;
    float bias = bL[0];
    for (int v = wid; v < n; v += nw) {
        int beg = off[v], end = off[v + 1];
        float dv = d[v];
        float l = 0.f, acc = 0.f;
        int i = beg + lane;
        for (; i + 192 < end; i += 256) {   // 4 edges in flight per lane
            int u0 = csr[i], u1 = csr[i + 64], u2 = csr[i + 128], u3 = csr[i + 192];
            float2 p0 = sh2[u0], p1 = sh2[u1], p2 = sh2[u2], p3 = sh2[u3];
            float t0 = p0.x + dv, t1 = p1.x + dv, t2 = p2.x + dv, t3 = p3.x + dv;
            t0 = t0 > 0.f ? t0 : NEG * t0; t1 = t1 > 0.f ? t1 : NEG * t1;
            t2 = t2 > 0.f ? t2 : NEG * t2; t3 = t3 > 0.f ? t3 : NEG * t3;
            float e0 = __expf(t0), e1 = __expf(t1), e2 = __expf(t2), e3 = __expf(t3);
            l += e0 + e1 + e2 + e3;
            acc += e0 * p0.y + e1 * p1.y + e2 * p2.y + e3 * p3.y;
        }
        for (; i < end; i += 64) {
            int u = csr[i];
            float2 p = sh2[u];
            float t = p.x + dv;
            t = t > 0.f ? t : NEG * t;
            float e = __expf(t);
            l += e;
            acc += e * p.y;
        }
#pragma unroll
        for (int o = 32; o > 0; o >>= 1) {
            l += __shfl_xor(l, o);
            acc += __shfl_xor(acc, o);
        }
        if (lane == 0) {
            float r = acc / l + bias;
            out[v] = 1.f / (1.f + __expf(-r));  // sigmoid
        }
    }
}

extern "C" void kernel_launch(void* const* d_in, const int* in_sizes, int n_in,
                              void* d_out, int out_size, void* d_ws, size_t ws_size,
                              hipStream_t stream) {
    const float* x   = (const float*)d_in[0];
    const int*   ei  = (const int*)d_in[1];
    // d_in[2] = edge_weight: ignored (edge_dim=None)
    const float* W0  = (const float*)d_in[3];
    const float* as0 = (const float*)d_in[4];
    const float* ad0 = (const float*)d_in[5];
    const float* b0  = (const float*)d_in[6];
    const float* Wm  = (const float*)d_in[7];
    const float* asm_ = (const float*)d_in[8];
    const float* adm = (const float*)d_in[9];
    const float* bm  = (const float*)d_in[10];
    const float* WL  = (const float*)d_in[11];
    const float* asL = (const float*)d_in[12];
    const float* adL = (const float*)d_in[13];
    const float* bL  = (const float*)d_in[14];

    const int n = in_sizes[0];      // 100000
    const int E = in_sizes[1] / 2;  // 6400000
    const int nb = (n + BNODES - 1) >> BSH;  // 196 buckets
    const int gChunk = (E + CH - 1) / CH;    // 391 chunks

    // workspace: h[n*64]f (hf8/sh2 alias; counts[] aliases during CSR build) |
    //            A[n*64]f (pairs[] aliases during CSR build) |
    //            s[n] | d[n] | off[n+1] | csr[E+n] | total[nb] | pbase[nb+1]
    float* ws   = (float*)d_ws;
    float* h    = ws;
    unsigned char* hf8 = (unsigned char*)ws;
    float2* sh2 = (float2*)ws;
    float* A    = ws + (size_t)n * HID;
    float* sbuf = ws + 2 * (size_t)n * HID;
    float* dbuf = sbuf + n;
    int* off    = (int*)(dbuf + n);
    int* csr    = off + n + 1;
    int* total  = csr + E + n;
    int* pbase  = total + nb;
    int* counts = (int*)h;            // gChunk*nb ints << region; pre-transform only
    unsigned* pairs = (unsigned*)A;   // E ints; pre-agg only

    const int BLK = 256;
    const int gTrans = 2048;
    const int gAgg   = (n + 3) / 4;   // 1 node per wave

    // ---- CSR build (deterministic bases; zero global atomics)
    chunk_hist_k<<<gChunk, BLK, 0, stream>>>(ei, E, nb, counts);
    col_scan_k<<<(nb + 3) / 4, BLK, 0, stream>>>(counts, gChunk, nb, total);
    bucket_scan_k<<<1, 1024, 0, stream>>>(total, pbase, nb);
    chunk_scatter_k<<<gChunk, BLK, 0, stream>>>(ei, E, nb, counts, pbase, pairs);
    csr_build_k<<<nb, 512, 0, stream>>>(pairs, pbase, nb, n, off, csr);

    // ---- layer 0: 1 -> 64, ReLU
    transform_k<1><<<gTrans, BLK, 0, stream>>>(x, W0, as0, ad0, hf8, sbuf, dbuf, n);
    gat_agg_k<<<gAgg, BLK, 0, stream>>>(off, csr, sbuf, dbuf, hf8, b0, A, n);

    // ---- middle layers: 64 -> 64, ReLU
    for (int l = 0; l < 3; ++l) {
        transform_k<64><<<gTrans, BLK, 0, stream>>>(A, Wm + (size_t)l * HID * HID,
                                                    asm_ + l * HID, adm + l * HID,
                                                    hf8, sbuf, dbuf, n);
        gat_agg_k<<<gAgg, BLK, 0, stream>>>(off, csr, sbuf, dbuf, hf8, bm + l * HID, A, n);
    }

    // ---- last layer: 64 -> 1, sigmoid ({s,hL} packed into sh2, aliasing h region)
    transform_last_k<<<gTrans, BLK, 0, stream>>>(A, WL, asL, adL, sh2, dbuf, n);
    gat_agg1_k<<<gAgg, BLK, 0, stream>>>(off, csr, sh2, dbuf, bL, (float*)d_out, n);
}

// Round 3
// 710.971 us; speedup vs baseline: 1.5991x; 1.3235x over previous
//
#include <hip/hip_runtime.h>
#include <math.h>

#define HID 64
#define NEG 0.2f
#define BSH 9         // bucket shift: 512 nodes per bucket
#define BNODES 512
#define CH 16384      // edges per chunk
#define NBMAX 256     // max buckets (n <= 131072)

typedef float f32x2 __attribute__((ext_vector_type(2)));
typedef float f32x4 __attribute__((ext_vector_type(4)));
typedef __bf16 bfx8 __attribute__((ext_vector_type(8)));

// ---------------- layer-0 node transform (CIN=1): hf8 = fp8(x@W), s, d
__global__ void transform0_k(const float* __restrict__ xin,
                             const float* __restrict__ W,      // [1][64]
                             const float* __restrict__ avs,
                             const float* __restrict__ avd,
                             unsigned char* __restrict__ hf8,  // [n][64] fp8 e4m3
                             float* __restrict__ s_out, float* __restrict__ d_out,
                             int n) {
    __shared__ float Wl[HID];
    __shared__ float asl[HID], adl[HID];
    if (threadIdx.x < HID) {
        Wl[threadIdx.x] = W[threadIdx.x];
        asl[threadIdx.x] = avs[threadIdx.x];
        adl[threadIdx.x] = avd[threadIdx.x];
    }
    __syncthreads();
    int lane = threadIdx.x & 63;
    int wid = (blockIdx.x * blockDim.x + threadIdx.x) >> 6;
    int nw = (gridDim.x * blockDim.x) >> 6;
    for (int i = wid; i < n; i += nw) {
        float hv = xin[i] * Wl[lane];
        int pk = __builtin_amdgcn_cvt_pk_fp8_f32(hv, hv, 0, false);  // HW RNE cvt
        hf8[(size_t)i * HID + lane] = (unsigned char)(pk & 0xff);
        float sv = hv * asl[lane], dv = hv * adl[lane];
#pragma unroll
        for (int off = 32; off > 0; off >>= 1) {
            sv += __shfl_xor(sv, off);
            dv += __shfl_xor(dv, off);
        }
        if (lane == 0) { s_out[i] = sv; d_out[i] = dv; }
    }
}

// ---------------- middle-layer transform via MFMA: h = A@W (bf16 16x16x32).
// Per wave: 16 nodes, 8 MFMAs (4 N-tiles x 2 K-steps). N-tile nt covers
// PERMUTED columns {4u+nt : u=0..15} so each lane's 16 C-values are 4 rows x
// 4 CONSECUTIVE channels (4m..4m+3): fp8 row write is 2x cvt_pk + one u32
// store, no transpose. C/D layout (HW-verified): col=lane&15,
// row=(lane>>4)*4+reg. A/B frags: lane holds 8 contiguous K at k=(lane>>4)*8.
// W frags pre-converted to bf16 once per block into 8KB LDS (keeps VGPRs low;
// R1 lesson: protect occupancy).
__global__ __launch_bounds__(256) void transform_mfma_k(
    const float* __restrict__ xin,   // [n][64] f32
    const float* __restrict__ W,     // [64][64] f32
    const float* __restrict__ avs, const float* __restrict__ avd,
    unsigned char* __restrict__ hf8,
    float* __restrict__ s_out, float* __restrict__ d_out,
    int n) {
    __shared__ bfx8 wfrag[8][64];    // [ks*4+nt][lane]
    int t = threadIdx.x;
    int lane = t & 63;
    int wsub = t >> 6;
    int m = lane & 15, g = lane >> 4;
    // one-time B-fragment build: combo co = ks*4+nt; wave wsub builds 2 combos
#pragma unroll
    for (int cc = 0; cc < 2; ++cc) {
        int co = wsub * 2 + cc;
        int ks = co >> 2, nt = co & 3;
        int c = 4 * m + nt;
        bfx8 f;
#pragma unroll
        for (int j = 0; j < 8; ++j) {
            int k = ks * 32 + g * 8 + j;
            f[j] = (__bf16)W[k * 64 + c];
        }
        wfrag[co][lane] = f;
    }
    __syncthreads();
    float4 as4 = *(const float4*)&avs[4 * m];
    float4 ad4 = *(const float4*)&avd[4 * m];
    int ntiles = (n + 15) >> 4;
    int wid = (blockIdx.x * blockDim.x + t) >> 6;
    int nw = (gridDim.x * blockDim.x) >> 6;
    for (int tile = wid; tile < ntiles; tile += nw) {
        int node0 = tile << 4;
        int row = node0 + m;
        int rl = row < n ? row : n - 1;
        const float* ap = xin + (size_t)rl * HID + g * 8;
        float4 x0 = *(const float4*)ap;
        float4 x1 = *(const float4*)(ap + 4);
        float4 x2 = *(const float4*)(ap + 32);
        float4 x3 = *(const float4*)(ap + 36);
        bfx8 a0, a1;
        a0[0] = (__bf16)x0.x; a0[1] = (__bf16)x0.y; a0[2] = (__bf16)x0.z; a0[3] = (__bf16)x0.w;
        a0[4] = (__bf16)x1.x; a0[5] = (__bf16)x1.y; a0[6] = (__bf16)x1.z; a0[7] = (__bf16)x1.w;
        a1[0] = (__bf16)x2.x; a1[1] = (__bf16)x2.y; a1[2] = (__bf16)x2.z; a1[3] = (__bf16)x2.w;
        a1[4] = (__bf16)x3.x; a1[5] = (__bf16)x3.y; a1[6] = (__bf16)x3.z; a1[7] = (__bf16)x3.w;
        f32x4 ac0 = {0.f, 0.f, 0.f, 0.f}, ac1 = {0.f, 0.f, 0.f, 0.f};
        f32x4 ac2 = {0.f, 0.f, 0.f, 0.f}, ac3 = {0.f, 0.f, 0.f, 0.f};
        ac0 = __builtin_amdgcn_mfma_f32_16x16x32_bf16(a0, wfrag[0][lane], ac0, 0, 0, 0);
        ac1 = __builtin_amdgcn_mfma_f32_16x16x32_bf16(a0, wfrag[1][lane], ac1, 0, 0, 0);
        ac2 = __builtin_amdgcn_mfma_f32_16x16x32_bf16(a0, wfrag[2][lane], ac2, 0, 0, 0);
        ac3 = __builtin_amdgcn_mfma_f32_16x16x32_bf16(a0, wfrag[3][lane], ac3, 0, 0, 0);
        ac0 = __builtin_amdgcn_mfma_f32_16x16x32_bf16(a1, wfrag[4][lane], ac0, 0, 0, 0);
        ac1 = __builtin_amdgcn_mfma_f32_16x16x32_bf16(a1, wfrag[5][lane], ac1, 0, 0, 0);
        ac2 = __builtin_amdgcn_mfma_f32_16x16x32_bf16(a1, wfrag[6][lane], ac2, 0, 0, 0);
        ac3 = __builtin_amdgcn_mfma_f32_16x16x32_bf16(a1, wfrag[7][lane], ac3, 0, 0, 0);
        // epilogue: lane holds h[node0+g*4+i][4m+nt] = ac_nt[i]
#pragma unroll
        for (int i = 0; i < 4; ++i) {
            int r = node0 + g * 4 + i;
            if (r < n) {
                unsigned w32 = (unsigned)__builtin_amdgcn_cvt_pk_fp8_f32(ac0[i], ac1[i], 0, false);
                w32 = (unsigned)__builtin_amdgcn_cvt_pk_fp8_f32(ac2[i], ac3[i], (int)w32, true);
                *(unsigned*)&hf8[(size_t)r * HID + 4 * m] = w32;
            }
            float ps = ac0[i] * as4.x + ac1[i] * as4.y + ac2[i] * as4.z + ac3[i] * as4.w;
            float pd = ac0[i] * ad4.x + ac1[i] * ad4.y + ac2[i] * ad4.z + ac3[i] * ad4.w;
#pragma unroll
            for (int o = 1; o < 16; o <<= 1) {
                ps += __shfl_xor(ps, o);
                pd += __shfl_xor(pd, o);
            }
            if (m == 0 && r < n) { s_out[r] = ps; d_out[r] = pd; }
        }
    }
}

// last layer transform: 64 -> 1; packs {s, hL} as float2 so agg1 does 1 gather/edge
__global__ void transform_last_k(const float* __restrict__ xin,
                                 const float* __restrict__ WL,
                                 const float* __restrict__ asL, const float* __restrict__ adL,
                                 float2* __restrict__ sh2,     // [n] {s_u, hL_u}
                                 float* __restrict__ d_out,
                                 int n) {
    __shared__ float Wl[HID];
    if (threadIdx.x < HID) Wl[threadIdx.x] = WL[threadIdx.x];
    __syncthreads();
    float aS = asL[0], aD = adL[0];
    int lane = threadIdx.x & 63;
    int wid = (blockIdx.x * blockDim.x + threadIdx.x) >> 6;
    int nw = (gridDim.x * blockDim.x) >> 6;
    for (int i = wid; i < n; i += nw) {
        float hv = xin[(size_t)i * HID + lane] * Wl[lane];
#pragma unroll
        for (int off = 32; off > 0; off >>= 1) hv += __shfl_xor(hv, off);
        if (lane == 0) {
            sh2[i] = make_float2(hv * aS, hv);
            d_out[i] = hv * aD;
        }
    }
}

// ---------------- CSR build: deterministic two-pass, ZERO global atomics ----------------
__global__ __launch_bounds__(256) void chunk_hist_k(const int* __restrict__ ei, int E, int nb,
                                                    int* __restrict__ counts) {
    __shared__ int lh[NBMAX];
    int t = threadIdx.x;
    int base = blockIdx.x * CH;
    int end = base + CH; if (end > E) end = E;
    for (int b = t; b < NBMAX; b += 256) lh[b] = 0;
    __syncthreads();
    for (int e = base + t; e < end; e += 256)
        atomicAdd(&lh[ei[E + e] >> BSH], 1);
    __syncthreads();
    for (int b = t; b < nb; b += 256)
        counts[(size_t)blockIdx.x * nb + b] = lh[b];
}

__global__ void col_scan_k(int* __restrict__ counts, int nchunks, int nb,
                           int* __restrict__ total) {
    int b = (blockIdx.x * blockDim.x + threadIdx.x) >> 6;
    int lane = threadIdx.x & 63;
    if (b >= nb) return;
    int run = 0;
    for (int c0 = 0; c0 < nchunks; c0 += 64) {
        int c = c0 + lane;
        int v = (c < nchunks) ? counts[(size_t)c * nb + b] : 0;
        int inc = v;
#pragma unroll
        for (int o = 1; o < 64; o <<= 1) {
            int w = __shfl_up(inc, o);
            if (lane >= o) inc += w;
        }
        int excl = inc - v + run;
        if (c < nchunks) counts[(size_t)c * nb + b] = excl;
        run += __shfl(inc, 63);
    }
    if (lane == 0) total[b] = run;
}

__global__ void bucket_scan_k(const int* __restrict__ total, int* __restrict__ pbase, int nb) {
    __shared__ int s[1024];
    int t = threadIdx.x;
    int v = (t < nb) ? total[t] : 0;
    s[t] = v;
    __syncthreads();
    for (int o = 1; o < 1024; o <<= 1) {
        int x = (t >= o) ? s[t - o] : 0;
        __syncthreads();
        s[t] += x;
        __syncthreads();
    }
    if (t < nb) {
        pbase[t] = s[t] - v;
        if (t == nb - 1) pbase[nb] = s[t];
    }
}

__global__ __launch_bounds__(256) void chunk_scatter_k(const int* __restrict__ ei, int E, int nb,
                                                       const int* __restrict__ counts,
                                                       const int* __restrict__ pbase,
                                                       unsigned* __restrict__ pairs) {
    __shared__ int lcur[NBMAX];
    int t = threadIdx.x;
    int c = blockIdx.x;
    int base = c * CH;
    int end = base + CH; if (end > E) end = E;
    for (int b = t; b < nb; b += 256)
        lcur[b] = pbase[b] + counts[(size_t)c * nb + b];
    __syncthreads();
    for (int e = base + t; e < end; e += 256) {
        int u = ei[e], v = ei[E + e];
        int b = v >> BSH;
        int pos = atomicAdd(&lcur[b], 1);
        pairs[pos] = ((unsigned)u << BSH) | (unsigned)(v & (BNODES - 1));
    }
}

__global__ __launch_bounds__(512) void csr_build_k(const unsigned* __restrict__ pairs,
                                                   const int* __restrict__ pbase,
                                                   int nb, int n,
                                                   int* __restrict__ off, int* __restrict__ csr) {
    __shared__ int cnt[BNODES];
    __shared__ int sc[BNODES];
    __shared__ int cur[BNODES];
    int b = blockIdx.x;
    int pb = pbase[b], pe = pbase[b + 1];
    int node0 = b << BSH;
    int nnode = n - node0; if (nnode > BNODES) nnode = BNODES;
    int cbase = pb + node0;
    int t = threadIdx.x;
    cnt[t] = 0;
    __syncthreads();
    for (int i = pb + t; i < pe; i += blockDim.x)
        atomicAdd(&cnt[pairs[i] & (BNODES - 1)], 1);
    __syncthreads();
    int deg = (t < nnode) ? cnt[t] + 1 : 0;   // +1 self loop
    sc[t] = deg;
    __syncthreads();
#pragma unroll
    for (int o = 1; o < BNODES; o <<= 1) {
        int x = (t >= o) ? sc[t - o] : 0;
        __syncthreads();
        sc[t] += x;
        __syncthreads();
    }
    if (t < nnode) {
        int excl = sc[t] - deg;
        off[node0 + t] = cbase + excl;
        cur[t] = excl;
        csr[cbase + excl + cnt[t]] = node0 + t;    // self-loop slot
    }
    if (b == nb - 1 && t == 0) off[n] = cbase + sc[BNODES - 1];
    __syncthreads();
    for (int i = pb + t; i < pe; i += blockDim.x) {
        unsigned p = pairs[i];
        int j = p & (BNODES - 1);
        int pos = atomicAdd(&cur[j], 1);
        csr[cbase + pos] = (int)(p >> BSH);
    }
}

// ---------------- fused softmax+aggregate (128-edge blocks, LDS exchange).
__global__ __launch_bounds__(256, 8) void gat_agg_k(
    const int* __restrict__ off, const int* __restrict__ csr,
    const float* __restrict__ s, const float* __restrict__ d,
    const unsigned char* __restrict__ hf8, const float* __restrict__ b,
    float* __restrict__ out, int n) {
    __shared__ uint2 eu_lds[4][128];
    int lane = threadIdx.x & 63;
    int wsub = threadIdx.x >> 6;
    int sub = lane & 7;         // channel group: channels sub*8 .. sub*8+7
    int q = lane >> 3;          // edge slot 0..7 (mod 8)
    int ch = sub * 8;
    int wid = (blockIdx.x * blockDim.x + threadIdx.x) >> 6;
    int nw = (gridDim.x * blockDim.x) >> 6;
    uint2* eup = eu_lds[wsub];
    float4 bb0 = *(const float4*)&b[ch];
    float4 bb1 = *(const float4*)&b[ch + 4];
    for (int v = wid; v < n; v += nw) {
        int beg = off[v];
        int deg = off[v + 1] - beg;
        float dv = d[v];
        float l = 0.f;
        f32x2 a01 = {0.f, 0.f}, a23 = {0.f, 0.f}, a45 = {0.f, 0.f}, a67 = {0.f, 0.f};
        for (int base = 0; base < deg; base += 128) {
            int rem = deg - base;
            int kmax = rem < 128 ? rem : 128;
            // phase 1: two independent edge chains per lane; exp once per edge
            unsigned ua = 0u, ub = 0u;
            float ea = 0.f, eb = 0.f;
            bool va = lane < kmax, vb = lane + 64 < kmax;
            if (va) ua = (unsigned)csr[beg + base + lane];
            if (vb) ub = (unsigned)csr[beg + base + 64 + lane];
            float sa = va ? s[ua] : 0.f;
            float sb = vb ? s[ub] : 0.f;
            if (va) {
                float t = sa + dv;
                t = t > 0.f ? t : NEG * t;
                ea = __expf(t);
            }
            if (vb) {
                float t = sb + dv;
                t = t > 0.f ? t : NEG * t;
                eb = __expf(t);
            }
            l += ea + eb;
            eup[lane] = make_uint2(__float_as_uint(ea), ua);
            eup[64 + lane] = make_uint2(__float_as_uint(eb), ub);
            // phase 2: uniform groups of 32 slots, 4 gathers in flight
            for (int k0 = 0; k0 < kmax; k0 += 32) {
                uint2 e0 = eup[k0 + q];
                uint2 e1 = eup[k0 + q + 8];
                uint2 e2 = eup[k0 + q + 16];
                uint2 e3 = eup[k0 + q + 24];
                uint2 h0 = *(const uint2*)&hf8[(size_t)e0.y * HID + ch];
                uint2 h1 = *(const uint2*)&hf8[(size_t)e1.y * HID + ch];
                uint2 h2 = *(const uint2*)&hf8[(size_t)e2.y * HID + ch];
                uint2 h3 = *(const uint2*)&hf8[(size_t)e3.y * HID + ch];
                f32x2 E;
                E.x = __uint_as_float(e0.x); E.y = E.x;
                a01 += E * (f32x2)__builtin_amdgcn_cvt_pk_f32_fp8(h0.x, false);
                a23 += E * (f32x2)__builtin_amdgcn_cvt_pk_f32_fp8(h0.x, true);
                a45 += E * (f32x2)__builtin_amdgcn_cvt_pk_f32_fp8(h0.y, false);
                a67 += E * (f32x2)__builtin_amdgcn_cvt_pk_f32_fp8(h0.y, true);
                E.x = __uint_as_float(e1.x); E.y = E.x;
                a01 += E * (f32x2)__builtin_amdgcn_cvt_pk_f32_fp8(h1.x, false);
                a23 += E * (f32x2)__builtin_amdgcn_cvt_pk_f32_fp8(h1.x, true);
                a45 += E * (f32x2)__builtin_amdgcn_cvt_pk_f32_fp8(h1.y, false);
                a67 += E * (f32x2)__builtin_amdgcn_cvt_pk_f32_fp8(h1.y, true);
                E.x = __uint_as_float(e2.x); E.y = E.x;
                a01 += E * (f32x2)__builtin_amdgcn_cvt_pk_f32_fp8(h2.x, false);
                a23 += E * (f32x2)__builtin_amdgcn_cvt_pk_f32_fp8(h2.x, true);
                a45 += E * (f32x2)__builtin_amdgcn_cvt_pk_f32_fp8(h2.y, false);
                a67 += E * (f32x2)__builtin_amdgcn_cvt_pk_f32_fp8(h2.y, true);
                E.x = __uint_as_float(e3.x); E.y = E.x;
                a01 += E * (f32x2)__builtin_amdgcn_cvt_pk_f32_fp8(h3.x, false);
                a23 += E * (f32x2)__builtin_amdgcn_cvt_pk_f32_fp8(h3.x, true);
                a45 += E * (f32x2)__builtin_amdgcn_cvt_pk_f32_fp8(h3.y, false);
                a67 += E * (f32x2)__builtin_amdgcn_cvt_pk_f32_fp8(h3.y, true);
            }
        }
        // reduce: acc over the 8 edge slots (q); l over all 64 lanes
#pragma unroll
        for (int o = 8; o < 64; o <<= 1) {
            a01.x += __shfl_xor(a01.x, o); a01.y += __shfl_xor(a01.y, o);
            a23.x += __shfl_xor(a23.x, o); a23.y += __shfl_xor(a23.y, o);
            a45.x += __shfl_xor(a45.x, o); a45.y += __shfl_xor(a45.y, o);
            a67.x += __shfl_xor(a67.x, o); a67.y += __shfl_xor(a67.y, o);
        }
#pragma unroll
        for (int o = 1; o < 64; o <<= 1) l += __shfl_xor(l, o);
        if (q == 0) {
            float inv = 1.f / l;
            float4 r0, r1;
            r0.x = a01.x * inv + bb0.x; r0.y = a01.y * inv + bb0.y;
            r0.z = a23.x * inv + bb0.z; r0.w = a23.y * inv + bb0.w;
            r1.x = a45.x * inv + bb1.x; r1.y = a45.y * inv + bb1.y;
            r1.z = a67.x * inv + bb1.z; r1.w = a67.y * inv + bb1.w;
            r0.x = r0.x > 0.f ? r0.x : 0.f; r0.y = r0.y > 0.f ? r0.y : 0.f;
            r0.z = r0.z > 0.f ? r0.z : 0.f; r0.w = r0.w > 0.f ? r0.w : 0.f;
            r1.x = r1.x > 0.f ? r1.x : 0.f; r1.y = r1.y > 0.f ? r1.y : 0.f;
            r1.z = r1.z > 0.f ? r1.z : 0.f; r1.w = r1.w > 0.f ? r1.w : 0.f;
            *(float4*)&out[(size_t)v * HID + ch] = r0;
            *(float4*)&out[(size_t)v * HID + ch + 4] = r1;
        }
    }
}

// last layer aggregate (1 channel): single gather/edge ({s,hL} packed), 4-way unroll
__global__ void gat_agg1_k(const int* __restrict__ off, const int* __restrict__ csr,
                           const float2* __restrict__ sh2, const float* __restrict__ d,
                           const float* __restrict__ bL,
                           float* __restrict__ out, int n) {
    int lane = threadIdx.x & 63;
    int wid = (blockIdx.x * blockDim.x + threadIdx.x) >> 6;
    int nw = (gridDim.x * blockDim.x) >> 6;
    float bias = bL[0];
    for (int v = wid; v < n; v += nw) {
        int beg = off[v], end = off[v + 1];
        float dv = d[v];
        float l = 0.f, acc = 0.f;
        int i = beg + lane;
        for (; i + 192 < end; i += 256) {   // 4 edges in flight per lane
            int u0 = csr[i], u1 = csr[i + 64], u2 = csr[i + 128], u3 = csr[i + 192];
            float2 p0 = sh2[u0], p1 = sh2[u1], p2 = sh2[u2], p3 = sh2[u3];
            float t0 = p0.x + dv, t1 = p1.x + dv, t2 = p2.x + dv, t3 = p3.x + dv;
            t0 = t0 > 0.f ? t0 : NEG * t0; t1 = t1 > 0.f ? t1 : NEG * t1;
            t2 = t2 > 0.f ? t2 : NEG * t2; t3 = t3 > 0.f ? t3 : NEG * t3;
            float e0 = __expf(t0), e1 = __expf(t1), e2 = __expf(t2), e3 = __expf(t3);
            l += e0 + e1 + e2 + e3;
            acc += e0 * p0.y + e1 * p1.y + e2 * p2.y + e3 * p3.y;
        }
        for (; i < end; i += 64) {
            int u = csr[i];
            float2 p = sh2[u];
            float t = p.x + dv;
            t = t > 0.f ? t : NEG * t;
            float e = __expf(t);
            l += e;
            acc += e * p.y;
        }
#pragma unroll
        for (int o = 32; o > 0; o >>= 1) {
            l += __shfl_xor(l, o);
            acc += __shfl_xor(acc, o);
        }
        if (lane == 0) {
            float r = acc / l + bias;
            out[v] = 1.f / (1.f + __expf(-r));  // sigmoid
        }
    }
}

extern "C" void kernel_launch(void* const* d_in, const int* in_sizes, int n_in,
                              void* d_out, int out_size, void* d_ws, size_t ws_size,
                              hipStream_t stream) {
    const float* x   = (const float*)d_in[0];
    const int*   ei  = (const int*)d_in[1];
    // d_in[2] = edge_weight: ignored (edge_dim=None)
    const float* W0  = (const float*)d_in[3];
    const float* as0 = (const float*)d_in[4];
    const float* ad0 = (const float*)d_in[5];
    const float* b0  = (const float*)d_in[6];
    const float* Wm  = (const float*)d_in[7];
    const float* asm_ = (const float*)d_in[8];
    const float* adm = (const float*)d_in[9];
    const float* bm  = (const float*)d_in[10];
    const float* WL  = (const float*)d_in[11];
    const float* asL = (const float*)d_in[12];
    const float* adL = (const float*)d_in[13];
    const float* bL  = (const float*)d_in[14];

    const int n = in_sizes[0];      // 100000
    const int E = in_sizes[1] / 2;  // 6400000
    const int nb = (n + BNODES - 1) >> BSH;  // 196 buckets
    const int gChunk = (E + CH - 1) / CH;    // 391 chunks

    // workspace: h[n*64]f (hf8/sh2 alias; counts[] aliases during CSR build) |
    //            A[n*64]f (pairs[] aliases during CSR build) |
    //            s[n] | d[n] | off[n+1] | csr[E+n] | total[nb] | pbase[nb+1]
    float* ws   = (float*)d_ws;
    float* h    = ws;
    unsigned char* hf8 = (unsigned char*)ws;
    float2* sh2 = (float2*)ws;
    float* A    = ws + (size_t)n * HID;
    float* sbuf = ws + 2 * (size_t)n * HID;
    float* dbuf = sbuf + n;
    int* off    = (int*)(dbuf + n);
    int* csr    = off + n + 1;
    int* total  = csr + E + n;
    int* pbase  = total + nb;
    int* counts = (int*)h;            // gChunk*nb ints << region; pre-transform only
    unsigned* pairs = (unsigned*)A;   // E ints; pre-agg only

    const int BLK = 256;
    const int gTrans = 2048;
    const int gAgg   = (n + 3) / 4;   // 1 node per wave
    const int ntiles = (n + 15) >> 4;
    const int gMfma  = (ntiles + 3) / 4;  // 1 tile (16 nodes) per wave

    // ---- CSR build (deterministic bases; zero global atomics)
    chunk_hist_k<<<gChunk, BLK, 0, stream>>>(ei, E, nb, counts);
    col_scan_k<<<(nb + 3) / 4, BLK, 0, stream>>>(counts, gChunk, nb, total);
    bucket_scan_k<<<1, 1024, 0, stream>>>(total, pbase, nb);
    chunk_scatter_k<<<gChunk, BLK, 0, stream>>>(ei, E, nb, counts, pbase, pairs);
    csr_build_k<<<nb, 512, 0, stream>>>(pairs, pbase, nb, n, off, csr);

    // ---- layer 0: 1 -> 64, ReLU
    transform0_k<<<gTrans, BLK, 0, stream>>>(x, W0, as0, ad0, hf8, sbuf, dbuf, n);
    gat_agg_k<<<gAgg, BLK, 0, stream>>>(off, csr, sbuf, dbuf, hf8, b0, A, n);

    // ---- middle layers: 64 -> 64, ReLU (MFMA transform)
    for (int l = 0; l < 3; ++l) {
        transform_mfma_k<<<gMfma, BLK, 0, stream>>>(A, Wm + (size_t)l * HID * HID,
                                                    asm_ + l * HID, adm + l * HID,
                                                    hf8, sbuf, dbuf, n);
        gat_agg_k<<<gAgg, BLK, 0, stream>>>(off, csr, sbuf, dbuf, hf8, bm + l * HID, A, n);
    }

    // ---- last layer: 64 -> 1, sigmoid ({s,hL} packed into sh2, aliasing h region)
    transform_last_k<<<gTrans, BLK, 0, stream>>>(A, WL, asL, adL, sh2, dbuf, n);
    gat_agg1_k<<<gAgg, BLK, 0, stream>>>(off, csr, sh2, dbuf, bL, (float*)d_out, n);
}